// Round 1
// baseline (632.030 us; speedup 1.0000x reference)
//
#include <hip/hip_runtime.h>
#include <hip/hip_bf16.h>

#define B_   64
#define CIN  2048
#define COUT 32
#define P    196      // 14*14
#define PPAD 224      // padded pixel count (7 * 32)
#define REP  1024
#define K1   (CIN*COUT)  // 65536

typedef float  f32x4  __attribute__((ext_vector_type(4)));
typedef __bf16 bf16x8 __attribute__((ext_vector_type(8)));
typedef __bf16 bf16x4 __attribute__((ext_vector_type(4)));

// ---- workspace layout (bytes) ----
#define OFF_AM     0                                   // float[64][32][224]
#define OFF_H6PRE  (OFF_AM + B_*COUT*PPAD*4)           // float[64][1024]
#define OFF_H7PRE  (OFF_H6PRE + B_*REP*4)              // float[64][1024]
#define ZERO_BYTES (OFF_H7PRE + B_*REP*4)              // memset prefix
#define OFF_POOLED ((size_t)ZERO_BYTES)                // bf16[64][65536]
#define OFF_H6B    (OFF_POOLED + (size_t)B_*K1*2)      // bf16[64][1024]

// ============================================================
// Kernel 1: conv3x3 -> am (no bias), fp32 atomic accumulate.
// Grid (8 cin-chunks, 64 b), block 256 (4 waves).
// Implicit GEMM: C[o][p] += sum_d sum_i W[o][i,d] * Xext[i][shift(p,d)]
// LDS: zero-padded 16x16 extended image per cin (no boundary masks).
// ============================================================
__global__ __launch_bounds__(256)
void conv_kernel(const float* __restrict__ x, const float* __restrict__ cw,
                 float* __restrict__ am) {
  __shared__ __bf16 XT[256][32];     // [ext_pixel][cin_local] 16 KB
  __shared__ __bf16 WL[9][32][32];   // [d][o][cin_local]      18 KB

  const int b     = blockIdx.y;
  const int chunk = blockIdx.x;          // 8 chunks of 256 cins
  const int t     = threadIdx.x;
  const int wv    = t >> 6;
  const int lane  = t & 63;
  const int q     = lane >> 4;
  const int ln    = lane & 15;
  const int ot    = wv >> 1;             // waves 0,1 -> o-tile 0; waves 2,3 -> o-tile 1
  const int w0    = wv & 1;              // p-tile parity

  f32x4 acc[7];
  #pragma unroll
  for (int i = 0; i < 7; i++) { f32x4 z = {0.f,0.f,0.f,0.f}; acc[i] = z; }

  const float* xb = x + (size_t)b * CIN * P;

  for (int s = 0; s < 8; s++) {
    const int i0 = chunk * 256 + s * 32;
    __syncthreads();   // previous stage's compute done before overwriting LDS
    // zero XT (borders stay zero)
    unsigned int* xz = (unsigned int*)&XT[0][0];
    #pragma unroll
    for (int idx = t; idx < 4096; idx += 256) xz[idx] = 0u;
    __syncthreads();
    // fill XT interior: x[b, i0+il, p] -> XT[(h+1)*16 + (w+1)][il]
    for (int idx = t; idx < 32 * P; idx += 256) {
      int il = idx / P;
      int p  = idx - il * P;
      float v = xb[(size_t)(i0 + il) * P + p];
      int h = p / 14, w = p - h * 14;
      XT[(h + 1) * 16 + (w + 1)][il] = (__bf16)v;
    }
    // fill WL: cw[o, i0+il, d] -> WL[d][o][il]   (reads are fully coalesced)
    for (int idx = t; idx < 9216; idx += 256) {
      int o  = idx / 288;
      int r  = idx - o * 288;
      int il = r / 9;
      int d  = r - il * 9;
      float v = cw[(size_t)o * (CIN * 9) + (size_t)(i0 + il) * 9 + d];
      WL[d][o][il] = (__bf16)v;
    }
    __syncthreads();

    // A-fragments for this wave's o-tile: 9 shifts
    bf16x8 af[9];
    #pragma unroll
    for (int d = 0; d < 9; d++)
      af[d] = *(const bf16x8*)&WL[d][ot * 16 + ln][q * 8];

    #pragma unroll
    for (int pi = 0; pi < 7; pi++) {
      int pt = w0 + 2 * pi;
      if (pt > 12) break;                 // odd waves get 6 tiles
      int p  = pt * 16 + ln;
      int pp = p < P ? p : P - 1;         // lanes past 196 compute garbage, masked at store
      int h  = pp / 14, w = pp - (pp / 14) * 14;
      #pragma unroll
      for (int d = 0; d < 9; d++) {
        int dy = d / 3, dx = d - (d / 3) * 3;
        bf16x8 bfr = *(const bf16x8*)&XT[(h + dy) * 16 + (w + dx)][q * 8];
        acc[pi] = __builtin_amdgcn_mfma_f32_16x16x32_bf16(af[d], bfr, acc[pi], 0, 0, 0);
      }
    }
  }

  // epilogue: atomic accumulate partial am
  #pragma unroll
  for (int pi = 0; pi < 7; pi++) {
    int pt = w0 + 2 * pi;
    if (pt > 12) break;
    int p = pt * 16 + ln;
    if (p < P) {
      #pragma unroll
      for (int r = 0; r < 4; r++) {
        int o = ot * 16 + q * 4 + r;      // C/D: row = 4*quad + reg
        atomicAdd(&am[((size_t)b * COUT + o) * PPAD + p], acc[pi][r]);
      }
    }
  }
}

// ============================================================
// Kernel 2: pooled[b][i][o] = (1/196) sum_p (am[b,o,p]+cb[o]) * x[b,i,p]
// MFMA: M=o(32), N=i, K=p(224 padded; am pad region is zero).
// Grid (8 i-groups, 64 b), block 256; wave handles 64 i (4 n-frags) x 2 o-tiles.
// Output bf16 in feat layout [b][i*32+o].
// ============================================================
__global__ __launch_bounds__(256)
void pooled_kernel(const float* __restrict__ x, const float* __restrict__ amp,
                   const float* __restrict__ cb, __bf16* __restrict__ pooled) {
  const int b    = blockIdx.y;
  const int ig   = blockIdx.x;
  const int t    = threadIdx.x;
  const int wv   = t >> 6;
  const int lane = t & 63;
  const int q    = lane >> 4;
  const int ln   = lane & 15;
  const int ibase = ig * 256 + wv * 64;

  f32x4 acc[2][4];
  #pragma unroll
  for (int a = 0; a < 2; a++)
    #pragma unroll
    for (int c = 0; c < 4; c++) { f32x4 z = {0.f,0.f,0.f,0.f}; acc[a][c] = z; }

  const float* amb = amp + (size_t)b * COUT * PPAD;
  const float* xb  = x + (size_t)b * CIN * P;
  const float cbv[2] = { cb[ln], cb[16 + ln] };

  for (int kc = 0; kc < 7; kc++) {
    const int k0 = kc * 32;
    bf16x8 af[2];
    if (kc < 6) {
      #pragma unroll
      for (int o2 = 0; o2 < 2; o2++) {
        const float* src = &amb[(size_t)(o2 * 16 + ln) * PPAD + k0 + q * 8];
        f32x4 v0 = *(const f32x4*)src;
        f32x4 v1 = *(const f32x4*)(src + 4);
        bf16x8 a;
        #pragma unroll
        for (int j = 0; j < 4; j++) { a[j] = (__bf16)(v0[j] + cbv[o2]); a[4 + j] = (__bf16)(v1[j] + cbv[o2]); }
        af[o2] = a;
      }
    } else {
      #pragma unroll
      for (int o2 = 0; o2 < 2; o2++) {
        bf16x8 a;
        #pragma unroll
        for (int j = 0; j < 8; j++) {
          int p = k0 + q * 8 + j;
          a[j] = (p < P) ? (__bf16)(amb[(size_t)(o2 * 16 + ln) * PPAD + p] + cbv[o2]) : (__bf16)0.f;
        }
        af[o2] = a;
      }
    }
    #pragma unroll
    for (int it = 0; it < 4; it++) {
      const int i = ibase + it * 16 + ln;
      bf16x8 bfr;
      if (kc < 6) {
        const float* src = &xb[(size_t)i * P + k0 + q * 8];
        f32x4 v0 = *(const f32x4*)src;
        f32x4 v1 = *(const f32x4*)(src + 4);
        #pragma unroll
        for (int j = 0; j < 4; j++) { bfr[j] = (__bf16)v0[j]; bfr[4 + j] = (__bf16)v1[j]; }
      } else {
        #pragma unroll
        for (int j = 0; j < 8; j++) {
          int p = k0 + q * 8 + j;
          bfr[j] = (p < P) ? (__bf16)xb[(size_t)i * P + p] : (__bf16)0.f;
        }
      }
      acc[0][it] = __builtin_amdgcn_mfma_f32_16x16x32_bf16(af[0], bfr, acc[0][it], 0, 0, 0);
      acc[1][it] = __builtin_amdgcn_mfma_f32_16x16x32_bf16(af[1], bfr, acc[1][it], 0, 0, 0);
    }
  }

  const float sc = 1.0f / 196.0f;
  #pragma unroll
  for (int o2 = 0; o2 < 2; o2++)
    #pragma unroll
    for (int it = 0; it < 4; it++) {
      const int i = ibase + it * 16 + ln;       // C col = i
      bf16x4 vv;
      #pragma unroll
      for (int r = 0; r < 4; r++) vv[r] = (__bf16)(acc[o2][it][r] * sc);
      *(bf16x4*)&pooled[(size_t)b * K1 + (size_t)i * COUT + o2 * 16 + q * 4] = vv;
    }
}

// ============================================================
// Kernel 3: h6pre += pooled @ w6^T  (M=64 b, N=1024 r, K=65536)
// Grid (4 n-blocks, 64 k-splits), block 256; w6 fp32->bf16 in-register.
// ============================================================
__global__ __launch_bounds__(256)
void gemm1_kernel(const __bf16* __restrict__ pooled, const float* __restrict__ w6,
                  float* __restrict__ h6pre) {
  const int nb   = blockIdx.x;
  const int ks   = blockIdx.y;
  const int t    = threadIdx.x;
  const int wv   = t >> 6;
  const int lane = t & 63;
  const int q    = lane >> 4;
  const int ln   = lane & 15;
  const int n0   = nb * 256 + wv * 64;

  f32x4 acc[4][4];
  #pragma unroll
  for (int a = 0; a < 4; a++)
    #pragma unroll
    for (int c = 0; c < 4; c++) { f32x4 z = {0.f,0.f,0.f,0.f}; acc[a][c] = z; }

  for (int kc = 0; kc < 32; kc++) {
    const int k0 = ks * 1024 + kc * 32;
    bf16x8 af[4];
    #pragma unroll
    for (int mi = 0; mi < 4; mi++)
      af[mi] = *(const bf16x8*)&pooled[(size_t)(mi * 16 + ln) * K1 + k0 + q * 8];
    #pragma unroll
    for (int ni = 0; ni < 4; ni++) {
      const float* src = &w6[(size_t)(n0 + ni * 16 + ln) * K1 + k0 + q * 8];
      f32x4 v0 = *(const f32x4*)src;
      f32x4 v1 = *(const f32x4*)(src + 4);
      bf16x8 bfr;
      #pragma unroll
      for (int j = 0; j < 4; j++) { bfr[j] = (__bf16)v0[j]; bfr[4 + j] = (__bf16)v1[j]; }
      #pragma unroll
      for (int mi = 0; mi < 4; mi++)
        acc[mi][ni] = __builtin_amdgcn_mfma_f32_16x16x32_bf16(af[mi], bfr, acc[mi][ni], 0, 0, 0);
    }
  }
  #pragma unroll
  for (int mi = 0; mi < 4; mi++)
    #pragma unroll
    for (int ni = 0; ni < 4; ni++)
      #pragma unroll
      for (int r = 0; r < 4; r++) {
        int bb = mi * 16 + q * 4 + r;           // row = b
        int rr = n0 + ni * 16 + ln;             // col = r
        atomicAdd(&h6pre[(size_t)bb * REP + rr], acc[mi][ni][r]);
      }
}

// ============================================================
// Kernel 4: h6b = bf16(relu(h6pre + b6))
// ============================================================
__global__ void h6act_kernel(const float* __restrict__ h6pre, const float* __restrict__ b6,
                             __bf16* __restrict__ h6b) {
  int idx = blockIdx.x * 256 + threadIdx.x;
  float v = h6pre[idx] + b6[idx & (REP - 1)];
  h6b[idx] = (__bf16)fmaxf(v, 0.f);
}

// ============================================================
// Kernel 5: h7pre += h6b @ w7^T  (M=64, N=1024, K=1024)
// Grid (16 n-blocks of 64, 16 k-splits of 64), block 256.
// ============================================================
__global__ __launch_bounds__(256)
void gemm2_kernel(const __bf16* __restrict__ h6b, const float* __restrict__ w7,
                  float* __restrict__ h7pre) {
  const int nb   = blockIdx.x;
  const int ks   = blockIdx.y;
  const int t    = threadIdx.x;
  const int wv   = t >> 6;
  const int lane = t & 63;
  const int q    = lane >> 4;
  const int ln   = lane & 15;
  const int n0   = nb * 64 + wv * 16;

  f32x4 acc[4];
  #pragma unroll
  for (int a = 0; a < 4; a++) { f32x4 z = {0.f,0.f,0.f,0.f}; acc[a] = z; }

  #pragma unroll
  for (int kc = 0; kc < 2; kc++) {
    const int k0 = ks * 64 + kc * 32;
    const float* src = &w7[(size_t)(n0 + ln) * REP + k0 + q * 8];
    f32x4 v0 = *(const f32x4*)src;
    f32x4 v1 = *(const f32x4*)(src + 4);
    bf16x8 bfr;
    #pragma unroll
    for (int j = 0; j < 4; j++) { bfr[j] = (__bf16)v0[j]; bfr[4 + j] = (__bf16)v1[j]; }
    #pragma unroll
    for (int mi = 0; mi < 4; mi++) {
      bf16x8 af = *(const bf16x8*)&h6b[(size_t)(mi * 16 + ln) * REP + k0 + q * 8];
      acc[mi] = __builtin_amdgcn_mfma_f32_16x16x32_bf16(af, bfr, acc[mi], 0, 0, 0);
    }
  }
  #pragma unroll
  for (int mi = 0; mi < 4; mi++)
    #pragma unroll
    for (int r = 0; r < 4; r++) {
      int bb = mi * 16 + q * 4 + r;
      atomicAdd(&h7pre[(size_t)bb * REP + n0 + ln], acc[mi][r]);
    }
}

// ============================================================
// Kernel 6: out = relu(h7pre + b7)
// ============================================================
__global__ void outact_kernel(const float* __restrict__ h7pre, const float* __restrict__ b7,
                              float* __restrict__ out) {
  int idx = blockIdx.x * 256 + threadIdx.x;
  float v = h7pre[idx] + b7[idx & (REP - 1)];
  out[idx] = fmaxf(v, 0.f);
}

extern "C" void kernel_launch(void* const* d_in, const int* in_sizes, int n_in,
                              void* d_out, int out_size, void* d_ws, size_t ws_size,
                              hipStream_t stream) {
  const float* x   = (const float*)d_in[0];
  const float* cw  = (const float*)d_in[1];
  const float* cb  = (const float*)d_in[2];
  const float* w6  = (const float*)d_in[3];
  const float* b6  = (const float*)d_in[4];
  const float* w7  = (const float*)d_in[5];
  const float* b7  = (const float*)d_in[6];
  float* out = (float*)d_out;

  char* ws = (char*)d_ws;
  float*  am     = (float*)(ws + OFF_AM);
  float*  h6pre  = (float*)(ws + OFF_H6PRE);
  float*  h7pre  = (float*)(ws + OFF_H7PRE);
  __bf16* pooled = (__bf16*)(ws + OFF_POOLED);
  __bf16* h6b    = (__bf16*)(ws + OFF_H6B);

  // zero the atomic-accumulation buffers (ws is poisoned 0xAA before each call)
  hipMemsetAsync(ws, 0, ZERO_BYTES, stream);

  conv_kernel  <<<dim3(8, 64),  256, 0, stream>>>(x, cw, am);
  pooled_kernel<<<dim3(8, 64),  256, 0, stream>>>(x, am, cb, pooled);
  gemm1_kernel <<<dim3(4, 64),  256, 0, stream>>>(pooled, w6, h6pre);
  h6act_kernel <<<256,          256, 0, stream>>>(h6pre, b6, h6b);
  gemm2_kernel <<<dim3(16, 16), 256, 0, stream>>>(h6b, w7, h7pre);
  outact_kernel<<<256,          256, 0, stream>>>(h7pre, b7, out);
}